// Round 7
// baseline (216.333 us; speedup 1.0000x reference)
//
#include <hip/hip_runtime.h>
#include <math.h>

// Problem constants (fixed by setup_inputs)
constexpr int HOPS  = 3;
constexpr int VOCAB = 50257;
constexpr int DIM   = 128;
constexpr int NB    = 32;         // batch
constexpr int NM    = 512;        // story slots
constexpr int NS    = 6;          // tokens per story slot
constexpr int NT    = 128;        // trees
constexpr int NL    = 64;         // tokens per tree
constexpr int SLOTS = NM + NT;    // 640
constexpr size_t TS = (size_t)VOCAB * DIM;              // fp32 table stride in C
constexpr size_t TABSTRIDE = (size_t)NB * SLOTS * DIM;  // msum per-table stride (fp16 elems)

// Dim-sharded fp16 tables: Ch2[x][v][3][16], x = dim-group (16 dims), 8 groups.
// One subtable = VOCAB*48 halfs = 4.6 MB ~= one XCD's L2. Gather blocks for
// group x are pinned to XCD x via blockIdx%8 (round-robin dispatch heuristic;
// correctness does not depend on the mapping).
constexpr int NG = 8;             // dim-groups
constexpr int GW = 16;            // dims per group
constexpr size_t CH_ELEMS = (size_t)VOCAB * 3 * DIM;    // 19,298,688 (same total)
constexpr int NE8 = (int)(CH_ELEMS / 8);                // 2,412,336 half8 granules

typedef _Float16 half8 __attribute__((ext_vector_type(8)));

constexpr int CONV_BLOCKS = 2048;
constexpr int TREE_B2   = NB * NT * NG / 4;     // 8192 (4 trees/block per group)
constexpr int STORY_GB  = (NB * NM + 11) / 12;  // 1366 group-blocks (12 slots each)
constexpr int STORY_B2  = STORY_GB * NG;        // 10928
constexpr int GATHER_B2 = TREE_B2 + STORY_B2;   // 19120  (TREE_B2 % 8 == 0)

// ---------------------------------------------------------------------------
// Kernel 1: fp32 -> fp16 conversion into the dim-sharded layout.
// Input loop identical to before (fully coalesced float4 pairs); only the
// output address changes. Each wave's stores form 8 contiguous 128 B regions.
// ---------------------------------------------------------------------------
__global__ __launch_bounds__(256) void convert_k(
    const float* __restrict__ C, _Float16* __restrict__ Ch2)
{
    for (int e8 = blockIdx.x * 256 + threadIdx.x; e8 < NE8; e8 += CONV_BLOCKS * 256) {
        const size_t base = (size_t)e8 * 8;
        const size_t v    = base / 384;
        const int    rem  = (int)(base % 384);
        const int    tab  = rem >> 7;             // 0..2
        const int    d    = rem & 127;            // 8-aligned
        const int    x    = d >> 4;               // dim-group
        const int    dl   = d & 15;               // 0 or 8 within group
        const float* src = C + (size_t)(1 + tab) * TS + v * DIM + d;
        float4 f0 = *(const float4*)(src);
        float4 f1 = *(const float4*)(src + 4);
        half8 h;
        h[0]=(_Float16)f0.x; h[1]=(_Float16)f0.y; h[2]=(_Float16)f0.z; h[3]=(_Float16)f0.w;
        h[4]=(_Float16)f1.x; h[5]=(_Float16)f1.y; h[6]=(_Float16)f1.z; h[7]=(_Float16)f1.w;
        const size_t out = (((size_t)x * VOCAB + v) * 3 + tab) * GW + dl;
        *(half8*)(Ch2 + out) = h;
    }
}

// ---------------------------------------------------------------------------
// Kernel 2: dim-sharded gather. Block's group x = blockIdx%8; the block only
// ever touches subtable x (4.6 MB -> XCD-L2 resident; ~7x token multiplicity
// becomes L2 hits). LDS combine phases are ordered with __syncthreads() --
// uniform across the block since all 4 waves take the same branch.
//   tree blocks: 4 trees/block, one tree per wave. lane -> (pair p=lane>>1,
//     octet=lane&1); pair -> (tab=p%3, k=p/3); 7 rounds cover tokens 10r+k
//     (invalid -> token 0 = PAD = zero row). LDS combine over k.
//   story blocks: 3 slots/wave (54 active lanes: tab=p%3, tok=(p/3)%6,
//     slot=p/18), single round, LDS combine over tok.
// ---------------------------------------------------------------------------
__global__ __launch_bounds__(256) void gather_k(
    const _Float16* __restrict__ Ch2, const int* __restrict__ story,
    const int* __restrict__ kb, _Float16* __restrict__ msum)
{
    __shared__ float shm [4][54][17];   // per-wave partials (+1 pad -> no conflicts)
    __shared__ float shm2[4][3][16];    // per-wave (tab, dim) sums

    const int wave = threadIdx.x >> 6, lane = threadIdx.x & 63;
    const int x = blockIdx.x & 7;                       // dim-group == XCD (heuristic)
    const _Float16* gbase = Ch2 + (size_t)x * VOCAB * (3 * GW);

    if (blockIdx.x < TREE_B2) {
        // ---- tree: g in [0,4096) ----
        const int g = (blockIdx.x >> 3) * 4 + wave;
        const int b = g >> 7, tr = g & (NT - 1);

        const int tok = kb[(size_t)g * NL + lane];      // all 64 tokens, coalesced

        const int p = lane >> 1, oct = lane & 1;
        const int tabL = p % 3, kL = p / 3;             // active: p < 30

        float acc[8] = {0,0,0,0,0,0,0,0};
        #pragma unroll
        for (int r = 0; r < 7; ++r) {
            const int ti = 10 * r + kL;                 // token index for this lane
            int s = __shfl(tok, ti & 63);
            if (ti >= 64 || p >= 30) s = 0;             // PAD row == 0: free guard
            const _Float16* ptr = gbase + ((size_t)s * 3 + tabL) * GW + oct * 8;
            half8 v = *(const half8*)ptr;
            #pragma unroll
            for (int j = 0; j < 8; ++j) acc[j] += (float)v[j];
        }
        if (p < 30) {
            #pragma unroll
            for (int j = 0; j < 8; ++j) shm[wave][p][oct * 8 + j] = acc[j];
        }
        __syncthreads();                                // partials visible
        if (lane < 48) {
            const int tab2 = lane >> 4, d2 = lane & 15;
            float s = 0.f;
            #pragma unroll
            for (int k = 0; k < 10; ++k) s += shm[wave][3 * k + tab2][d2];
            shm2[wave][tab2][d2] = s;
        }
        __syncthreads();                                // sums visible
        if (lane < 6) {
            const int tab3 = lane >> 1, oct3 = lane & 1;
            half8 h;
            #pragma unroll
            for (int j = 0; j < 8; ++j) h[j] = (_Float16)shm2[wave][tab3][oct3 * 8 + j];
            const size_t o = ((size_t)b * SLOTS + NM + tr) * DIM + x * GW + oct3 * 8;
            *(half8*)(msum + o + (size_t)tab3 * TABSTRIDE) = h;
        }
    } else {
        // ---- story: 12 slots per group-block, 3 per wave ----
        const int gb = (blockIdx.x - TREE_B2) >> 3;
        const int s0 = gb * 12 + wave * 3;              // first slot, [0, 16392)
        const int rem = NB * NM - s0;
        const int nv = rem < 0 ? 0 : (rem < 3 ? rem : 3);

        const int tokv = (lane < nv * NS && lane < 18)
                       ? story[(size_t)s0 * NS + lane] : 0;   // 18 coalesced ints

        const int p = lane;                             // active: p < 54
        const int tabL = p % 3, tkL = (p / 3) % 6, slL = p / 18;
        int s = 0;
        if (p < 54) s = __shfl(tokv, slL * NS + tkL);   // invalid slots -> 0 (PAD)

        const _Float16* ptr = gbase + ((size_t)s * 3 + tabL) * GW;
        half8 v0 = *(const half8*)(ptr);
        half8 v1 = *(const half8*)(ptr + 8);
        if (p < 54) {
            #pragma unroll
            for (int j = 0; j < 8; ++j) {
                shm[wave][p][j]     = (float)v0[j];
                shm[wave][p][8 + j] = (float)v1[j];
            }
        }
        #pragma unroll
        for (int s3 = 0; s3 < 3; ++s3) {
            __syncthreads();                            // rows visible / WAR fence
            if (lane < 48) {
                const int tab2 = lane >> 4, d2 = lane & 15;
                float sum = 0.f;
                #pragma unroll
                for (int t = 0; t < NS; ++t)
                    sum += shm[wave][s3 * 18 + t * 3 + tab2][d2];
                shm2[wave][tab2][d2] = sum;
            }
            __syncthreads();                            // sums visible
            if (lane < 6 && s3 < nv) {
                const int tab3 = lane >> 1, oct3 = lane & 1;
                const int sg = s0 + s3;
                const int bb = sg >> 9, sl = sg & (NM - 1);
                half8 h;
                #pragma unroll
                for (int j = 0; j < 8; ++j) h[j] = (_Float16)shm2[wave][tab3][oct3 * 8 + j];
                const size_t o = ((size_t)bb * SLOTS + sl) * DIM + x * GW + oct3 * 8;
                *(half8*)(msum + o + (size_t)tab3 * TABSTRIDE) = h;
            }
        }
    }
}

// ---------------------------------------------------------------------------
// Fused hop chain (unchanged): one 1024-thread block per batch element,
// vc register-cache so each msum table is read exactly once.
// ---------------------------------------------------------------------------
__global__ __launch_bounds__(1024) void hops_fused(
    const _Float16* __restrict__ msum, float* __restrict__ out)
{
    const int b = blockIdx.x, t = threadIdx.x;
    const int rg = t >> 4, l16 = t & 15, wv = t >> 6, ln = t & 63;
    __shared__ float u_s[DIM];
    __shared__ float probs[SLOTS];
    __shared__ float part[64][DIM + 4];
    __shared__ float red[16];

    const _Float16* base = msum + (size_t)b * SLOTS * DIM;
    const int doff = l16 * 8;

    half8 vc[10];

    {
        float acc[8] = {0,0,0,0,0,0,0,0};
        #pragma unroll
        for (int r = 0; r < 10; ++r)
            vc[r] = *(const half8*)(base + (size_t)(rg + 64 * r) * DIM + doff);
        #pragma unroll
        for (int r = 0; r < 10; ++r) {
            #pragma unroll
            for (int j = 0; j < 8; ++j) acc[j] += (float)vc[r][j];
        }
        #pragma unroll
        for (int j = 0; j < 8; ++j) part[rg][doff + j] = acc[j];
        __syncthreads();
        if (t < DIM) {
            float s = 0.f;
            #pragma unroll
            for (int r = 0; r < 64; ++r) s += part[r][t];
            u_s[t] = s * (1.f / SLOTS);
        }
        __syncthreads();
    }

    #pragma unroll
    for (int hop = 1; hop < HOPS; ++hop) {
        float u_reg[8];
        #pragma unroll
        for (int j = 0; j < 8; ++j) u_reg[j] = u_s[doff + j];

        #pragma unroll
        for (int r = 0; r < 10; ++r) {
            const int m = rg + 64 * r;
            float d = 0.f;
            #pragma unroll
            for (int j = 0; j < 8; ++j) d = fmaf((float)vc[r][j], u_reg[j], d);
            d += __shfl_xor(d, 1); d += __shfl_xor(d, 2);
            d += __shfl_xor(d, 4); d += __shfl_xor(d, 8);
            if (l16 == 0) probs[m] = d;
        }
        __syncthreads();

        float s0 = (t < SLOTS) ? probs[t] : -INFINITY;
        float lmax = s0;
        #pragma unroll
        for (int off = 32; off > 0; off >>= 1) lmax = fmaxf(lmax, __shfl_xor(lmax, off));
        if (ln == 0) red[wv] = lmax;
        __syncthreads();
        lmax = red[0];
        #pragma unroll
        for (int r = 1; r < 16; ++r) lmax = fmaxf(lmax, red[r]);
        __syncthreads();
        float e0 = (t < SLOTS) ? expf(s0 - lmax) : 0.f;
        if (t < SLOTS) probs[t] = e0;
        float lsum = e0;
        #pragma unroll
        for (int off = 32; off > 0; off >>= 1) lsum += __shfl_xor(lsum, off);
        if (ln == 0) red[wv] = lsum;
        __syncthreads();
        float tot = red[0];
        #pragma unroll
        for (int r = 1; r < 16; ++r) tot += red[r];
        const float inv = 1.0f / tot;

        const _Float16* mC = base + (size_t)hop * TABSTRIDE;
        float acc[8] = {0,0,0,0,0,0,0,0};
        #pragma unroll
        for (int r = 0; r < 10; ++r) {
            const int m = rg + 64 * r;
            vc[r] = *(const half8*)(mC + (size_t)m * DIM + doff);
            const float p = probs[m];
            #pragma unroll
            for (int j = 0; j < 8; ++j) acc[j] = fmaf(p, (float)vc[r][j], acc[j]);
        }
        __syncthreads();
        #pragma unroll
        for (int j = 0; j < 8; ++j) part[rg][doff + j] = acc[j];
        __syncthreads();
        if (t < DIM) {
            float s = 0.f;
            #pragma unroll
            for (int r = 0; r < 64; ++r) s += part[r][t];
            u_s[t] += s * inv;
        }
        __syncthreads();
    }

    if (t < DIM) out[b * DIM + t] = u_s[t];
}

extern "C" void kernel_launch(void* const* d_in, const int* in_sizes, int n_in,
                              void* d_out, int out_size, void* d_ws, size_t ws_size,
                              hipStream_t stream) {
    const float* C     = (const float*)d_in[0];   // [4][VOCAB][DIM] fp32
    const int*   story = (const int*)d_in[1];     // [32][512][6]
    const int*   kb    = (const int*)d_in[2];     // [32][128][64]
    float*       out   = (float*)d_out;           // [32][128] fp32

    _Float16* Ch2  = (_Float16*)d_ws;             // [8][V][3][16] fp16 = 36.8 MiB
    _Float16* msum = Ch2 + CH_ELEMS;              // [3][NB][SLOTS][128] fp16 = 15 MiB

    convert_k<<<CONV_BLOCKS, 256, 0, stream>>>(C, Ch2);
    gather_k<<<GATHER_B2, 256, 0, stream>>>(Ch2, story, kb, msum);
    hops_fused<<<NB, 1024, 0, stream>>>(msum, out);
}